// Round 2
// baseline (1408.127 us; speedup 1.0000x reference)
//
#include <hip/hip_runtime.h>
#include <stdint.h>

#define HIDN 256
#define ROWS 16

// ---------------- flag scatter ----------------
__global__ void k_flag(const int* __restrict__ targets, unsigned char* __restrict__ flag, int T) {
    int t = blockIdx.x * blockDim.x + threadIdx.x;
    if (t < T) flag[targets[t]] = 1;
}

// ---------------- edge logits + segment max ----------------
__global__ __launch_bounds__(256) void k_edge_logits(
    const float* __restrict__ h, const float* __restrict__ attn,
    const int* __restrict__ src, const int* __restrict__ dst,
    const unsigned char* __restrict__ flag,
    float* __restrict__ e_buf, unsigned int* __restrict__ m, int E)
{
    int tid = blockIdx.x * blockDim.x + threadIdx.x;
    int edge = tid >> 3;
    int lane = tid & 7;
    if (edge >= E) return;
    int d = dst[edge];
    if (!flag[d]) return;
    int s = src[edge];
    const float* hp = h + (size_t)s * 64 + lane * 8;
    const float* ap = attn + lane * 8;
    float4 h0 = *(const float4*)(hp);
    float4 h1 = *(const float4*)(hp + 4);
    float4 a0 = *(const float4*)(ap);
    float4 a1 = *(const float4*)(ap + 4);
    float sum = h0.x * a0.x + h0.y * a0.y + h0.z * a0.z + h0.w * a0.w
              + h1.x * a1.x + h1.y * a1.y + h1.z * a1.z + h1.w * a1.w;
    sum += __shfl_xor(sum, 1);
    sum += __shfl_xor(sum, 2);
    sum += __shfl_xor(sum, 4);
    if (lane == 0) {
        float e = fmaxf(sum, 0.f);
        e_buf[edge] = e;
        // e >= 0, so float ordering == uint ordering; m zero-initialized (== 0.0f)
        atomicMax(m + d, __float_as_uint(e));
    }
}

// ---------------- exp + segment sum ----------------
__global__ __launch_bounds__(256) void k_edge_exp(
    const int* __restrict__ dst, const unsigned char* __restrict__ flag,
    const float* __restrict__ m, float* __restrict__ e_buf,
    float* __restrict__ denom, int E)
{
    int i = blockIdx.x * blockDim.x + threadIdx.x;
    if (i >= E) return;
    int d = dst[i];
    if (!flag[d]) return;
    float ex = __expf(e_buf[i] - m[d]);
    e_buf[i] = ex;
    atomicAdd(denom + d, ex);
}

// ---------------- weighted scatter-accumulate ----------------
__global__ __launch_bounds__(256) void k_edge_accum(
    const float* __restrict__ h,
    const int* __restrict__ src, const int* __restrict__ dst,
    const unsigned char* __restrict__ flag,
    const float* __restrict__ e_buf, const float* __restrict__ denom,
    float* __restrict__ h_neigh, int E)
{
    int tid = blockIdx.x * blockDim.x + threadIdx.x;
    int edge = tid >> 3;
    int lane = tid & 7;
    if (edge >= E) return;
    int d = dst[edge];
    if (!flag[d]) return;
    float a = e_buf[edge] / denom[d];
    int s = src[edge];
    const float* hp = h + (size_t)s * 64 + lane * 8;
    float4 h0 = *(const float4*)(hp);
    float4 h1 = *(const float4*)(hp + 4);
    float* outp = h_neigh + (size_t)d * 64 + lane * 8;
    atomicAdd(outp + 0, h0.x * a);
    atomicAdd(outp + 1, h0.y * a);
    atomicAdd(outp + 2, h0.z * a);
    atomicAdd(outp + 3, h0.w * a);
    atomicAdd(outp + 4, h1.x * a);
    atomicAdd(outp + 5, h1.y * a);
    atomicAdd(outp + 6, h1.z * a);
    atomicAdd(outp + 7, h1.w * a);
}

// ---------------- fused 2x MLP + relu + target gather ----------------
__global__ __launch_bounds__(256) void k_mlp(
    const float* __restrict__ h_neigh, const float* __restrict__ cell_feat,
    const float* __restrict__ Wn1, const float* __restrict__ bn1,
    const float* __restrict__ Wn2, const float* __restrict__ bn2,
    const float* __restrict__ Ws1, const float* __restrict__ bs1,
    const float* __restrict__ Ws2, const float* __restrict__ bs2,
    const int* __restrict__ targets, float* __restrict__ out, int T)
{
    __shared__ float xn[ROWS][64];
    __shared__ float xs[ROWS][64];
    __shared__ float hn[ROWS][HIDN];
    __shared__ float hs[ROWS][HIDN];
    const int t = threadIdx.x;
    const int row0 = blockIdx.x * ROWS;

    // stage x (16 threads per row, 4 feats each)
    {
        int r = t >> 4;
        int q = t & 15;
        int grow = row0 + r;
        if (grow < T) {
            int g = targets[grow];
            *(float4*)&xn[r][q * 4] = *(const float4*)(h_neigh + (size_t)g * 64 + q * 4);
            *(float4*)&xs[r][q * 4] = *(const float4*)(cell_feat + (size_t)g * 64 + q * 4);
        } else {
            *(float4*)&xn[r][q * 4] = make_float4(0.f, 0.f, 0.f, 0.f);
            *(float4*)&xs[r][q * 4] = make_float4(0.f, 0.f, 0.f, 0.f);
        }
    }
    __syncthreads();

    // layer 1: thread t owns hidden unit t for both MLPs, all ROWS rows
    float accn[ROWS], accs[ROWS];
#pragma unroll
    for (int r = 0; r < ROWS; r++) { accn[r] = 0.f; accs[r] = 0.f; }
    for (int d4 = 0; d4 < 16; d4++) {
        float wn[4], ws[4];
#pragma unroll
        for (int i = 0; i < 4; i++) {
            wn[i] = Wn1[(size_t)(d4 * 4 + i) * HIDN + t];
            ws[i] = Ws1[(size_t)(d4 * 4 + i) * HIDN + t];
        }
#pragma unroll
        for (int r = 0; r < ROWS; r++) {
            float4 xv = *(const float4*)&xn[r][d4 * 4];
            float4 sv = *(const float4*)&xs[r][d4 * 4];
            accn[r] += xv.x * wn[0] + xv.y * wn[1] + xv.z * wn[2] + xv.w * wn[3];
            accs[r] += sv.x * ws[0] + sv.y * ws[1] + sv.z * ws[2] + sv.w * ws[3];
        }
    }
    {
        float b1n = bn1[t];
        float b1s = bs1[t];
#pragma unroll
        for (int r = 0; r < ROWS; r++) {
            hn[r][t] = fmaxf(accn[r] + b1n, 0.f);
            hs[r][t] = fmaxf(accs[r] + b1s, 0.f);
        }
    }
    __syncthreads();

    // layer 2: thread t -> output col j = t&63, rows rg..rg+3 (full K dot)
    const int j = t & 63;
    const int rg = (t >> 6) * 4;
    float acc[4] = {0.f, 0.f, 0.f, 0.f};
    for (int k4 = 0; k4 < HIDN / 4; k4++) {
        float wn2[4], ws2[4];
#pragma unroll
        for (int i = 0; i < 4; i++) {
            wn2[i] = Wn2[(size_t)(k4 * 4 + i) * 64 + j];
            ws2[i] = Ws2[(size_t)(k4 * 4 + i) * 64 + j];
        }
#pragma unroll
        for (int r = 0; r < 4; r++) {
            float4 hv = *(const float4*)&hn[rg + r][k4 * 4];
            float4 sv = *(const float4*)&hs[rg + r][k4 * 4];
            acc[r] += hv.x * wn2[0] + hv.y * wn2[1] + hv.z * wn2[2] + hv.w * wn2[3]
                    + sv.x * ws2[0] + sv.y * ws2[1] + sv.z * ws2[2] + sv.w * ws2[3];
        }
    }
    {
        float b2 = bn2[j] + bs2[j];
#pragma unroll
        for (int r = 0; r < 4; r++) {
            int grow = row0 + rg + r;
            if (grow < T) {
                out[(size_t)grow * 64 + j] = fmaxf(acc[r] + b2, 0.f);
            }
        }
    }
}

extern "C" void kernel_launch(void* const* d_in, const int* in_sizes, int n_in,
                              void* d_out, int out_size, void* d_ws, size_t ws_size,
                              hipStream_t stream)
{
    const float* h    = (const float*)d_in[0];
    const float* cf   = (const float*)d_in[1];
    const float* attn = (const float*)d_in[2];
    const float* Wn1  = (const float*)d_in[3];
    const float* bn1  = (const float*)d_in[4];
    const float* Wn2  = (const float*)d_in[5];
    const float* bn2  = (const float*)d_in[6];
    const float* Ws1  = (const float*)d_in[7];
    const float* bs1  = (const float*)d_in[8];
    const float* Ws2  = (const float*)d_in[9];
    const float* bs2  = (const float*)d_in[10];
    const int* src     = (const int*)d_in[11];
    const int* dst     = (const int*)d_in[12];
    const int* targets = (const int*)d_in[13];
    const int N = in_sizes[0] / 64;
    const int E = in_sizes[11];
    const int T = in_sizes[13];

    char* ws = (char*)d_ws;
    float*         h_neigh = (float*)ws;                                   // N*64*4 bytes
    float*         m       = (float*)(ws + (size_t)N * 256);               // N*4
    float*         denom   = (float*)(ws + (size_t)N * 256 + (size_t)N * 4);
    unsigned char* flag    = (unsigned char*)(ws + (size_t)N * 256 + (size_t)N * 8);
    float*         e_buf   = (float*)(ws + (size_t)N * 256 + (size_t)N * 8 + (size_t)N);

    // zero h_neigh, m, denom, flag in one memset (contiguous prefix of ws)
    size_t zbytes = (size_t)N * 256 + (size_t)N * 8 + (size_t)N;
    hipMemsetAsync(d_ws, 0, zbytes, stream);

    k_flag<<<(T + 255) / 256, 256, 0, stream>>>(targets, flag, T);
    {
        long long thr = (long long)E * 8;
        k_edge_logits<<<(unsigned)((thr + 255) / 256), 256, 0, stream>>>(
            h, attn, src, dst, flag, e_buf, (unsigned int*)m, E);
    }
    k_edge_exp<<<(E + 255) / 256, 256, 0, stream>>>(dst, flag, m, e_buf, denom, E);
    {
        long long thr = (long long)E * 8;
        k_edge_accum<<<(unsigned)((thr + 255) / 256), 256, 0, stream>>>(
            h, src, dst, flag, e_buf, denom, h_neigh, E);
    }
    k_mlp<<<(T + ROWS - 1) / ROWS, 256, 0, stream>>>(
        h_neigh, cf, Wn1, bn1, Wn2, bn2, Ws1, bs1, Ws2, bs2,
        targets, (float*)d_out, T);
}

// Round 3
// 694.194 us; speedup vs baseline: 2.0284x; 2.0284x over previous
//
#include <hip/hip_runtime.h>
#include <stdint.h>

#define HIDN 256
#define ROWS 16
#define SBS 512

// ---------------- unique-target list + slot map ----------------
__global__ __launch_bounds__(256) void k_flag_list(
    const int* __restrict__ targets, int* __restrict__ flag,
    int* __restrict__ slot, int* __restrict__ count, int T)
{
    int t = blockIdx.x * blockDim.x + threadIdx.x;
    if (t >= T) return;
    int g = targets[t];
    int old = atomicExch(&flag[g], 1);
    if (old == 0) {
        int u = atomicAdd(count, 1);
        slot[g] = u;
    }
}

// ---------------- per-slot in-degree histogram ----------------
__global__ __launch_bounds__(256) void k_hist(
    const int* __restrict__ dst, const int* __restrict__ flag,
    const int* __restrict__ slot, int* __restrict__ cnt, int E)
{
    int e = blockIdx.x * blockDim.x + threadIdx.x;
    if (e >= E) return;
    int d = dst[e];
    if (!flag[d]) return;
    atomicAdd(&cnt[slot[d]], 1);
}

// ---------------- exclusive scan (3-kernel, fixed length T) ----------------
__global__ __launch_bounds__(SBS) void k_scan1(
    const int* __restrict__ cnt, int* __restrict__ offs, int* __restrict__ bsum, int n)
{
    __shared__ int s[SBS];
    int t = threadIdx.x, i = blockIdx.x * SBS + t;
    int v = (i < n) ? cnt[i] : 0;
    s[t] = v; __syncthreads();
    for (int off = 1; off < SBS; off <<= 1) {
        int x = (t >= off) ? s[t - off] : 0; __syncthreads();
        s[t] += x; __syncthreads();
    }
    if (i < n) offs[i] = s[t] - v;
    if (t == SBS - 1) bsum[blockIdx.x] = s[t];
}
__global__ __launch_bounds__(1024) void k_scan2(int* __restrict__ bsum, int nb)
{
    __shared__ int s[1024];
    int t = threadIdx.x;
    int v = (t < nb) ? bsum[t] : 0;
    s[t] = v; __syncthreads();
    for (int off = 1; off < 1024; off <<= 1) {
        int x = (t >= off) ? s[t - off] : 0; __syncthreads();
        s[t] += x; __syncthreads();
    }
    if (t < nb) bsum[t] = s[t] - v;
}
__global__ __launch_bounds__(SBS) void k_scan3(
    int* __restrict__ offs, const int* __restrict__ bsum, int n)
{
    int i = blockIdx.x * SBS + threadIdx.x;
    if (i < n) offs[i] += bsum[blockIdx.x];
}

// ---------------- CSR edge scatter (stores src ids) ----------------
__global__ __launch_bounds__(256) void k_scatter(
    const int* __restrict__ src, const int* __restrict__ dst,
    const int* __restrict__ flag, const int* __restrict__ slot,
    const int* __restrict__ offs, int* __restrict__ cursor,
    int* __restrict__ esrc, int E)
{
    int e = blockIdx.x * blockDim.x + threadIdx.x;
    if (e >= E) return;
    int d = dst[e];
    if (!flag[d]) return;
    int sl = slot[d];
    int pos = atomicAdd(&cursor[sl], 1);
    esrc[offs[sl] + pos] = src[e];
}

// ---------------- gather: per-node online softmax + weighted sum ----------------
// 16 lanes per unique node, 4 feats per lane.
__global__ __launch_bounds__(256) void k_gather(
    const float* __restrict__ h, const float* __restrict__ attn,
    const int* __restrict__ offs, const int* __restrict__ cnt,
    const int* __restrict__ esrc, const int* __restrict__ count,
    float* __restrict__ hnc, int T)
{
    int tid = blockIdx.x * blockDim.x + threadIdx.x;
    int gid = tid >> 4;           // slot index
    int lane = tid & 15;
    const int U = count[0];
    if (gid >= U) return;
    int start = offs[gid];
    int n = cnt[gid];
    float4 av = *(const float4*)(attn + lane * 4);
    float m = 0.f, den = 0.f;
    float4 o = make_float4(0.f, 0.f, 0.f, 0.f);
    for (int j = 0; j < n; j++) {
        int s = esrc[start + j];
        float4 hv = *(const float4*)(h + (size_t)s * 64 + lane * 4);
        float p = hv.x * av.x + hv.y * av.y + hv.z * av.z + hv.w * av.w;
        p += __shfl_xor(p, 1);
        p += __shfl_xor(p, 2);
        p += __shfl_xor(p, 4);
        p += __shfl_xor(p, 8);
        float e = fmaxf(p, 0.f);
        float mn = fmaxf(m, e);
        float corr = __expf(m - mn);
        float w = __expf(e - mn);
        den = den * corr + w;
        o.x = o.x * corr + w * hv.x;
        o.y = o.y * corr + w * hv.y;
        o.z = o.z * corr + w * hv.z;
        o.w = o.w * corr + w * hv.w;
        m = mn;
    }
    float4 r = make_float4(0.f, 0.f, 0.f, 0.f);
    if (n > 0) {
        float inv = 1.f / den;
        r = make_float4(o.x * inv, o.y * inv, o.z * inv, o.w * inv);
    }
    *(float4*)(hnc + (size_t)gid * 64 + lane * 4) = r;
}

// ---------------- fused 2x MLP + relu + target gather ----------------
__global__ __launch_bounds__(256) void k_mlp(
    const float* __restrict__ hnc, const int* __restrict__ slot,
    const float* __restrict__ cell_feat,
    const float* __restrict__ Wn1, const float* __restrict__ bn1,
    const float* __restrict__ Wn2, const float* __restrict__ bn2,
    const float* __restrict__ Ws1, const float* __restrict__ bs1,
    const float* __restrict__ Ws2, const float* __restrict__ bs2,
    const int* __restrict__ targets, float* __restrict__ out, int T)
{
    __shared__ float xn[ROWS][64];
    __shared__ float xs[ROWS][64];
    __shared__ float hn[ROWS][HIDN];
    __shared__ float hs[ROWS][HIDN];
    const int t = threadIdx.x;
    const int row0 = blockIdx.x * ROWS;

    {
        int r = t >> 4;
        int q = t & 15;
        int grow = row0 + r;
        if (grow < T) {
            int g = targets[grow];
            int sl = slot[g];
            *(float4*)&xn[r][q * 4] = *(const float4*)(hnc + (size_t)sl * 64 + q * 4);
            *(float4*)&xs[r][q * 4] = *(const float4*)(cell_feat + (size_t)g * 64 + q * 4);
        } else {
            *(float4*)&xn[r][q * 4] = make_float4(0.f, 0.f, 0.f, 0.f);
            *(float4*)&xs[r][q * 4] = make_float4(0.f, 0.f, 0.f, 0.f);
        }
    }
    __syncthreads();

    float accn[ROWS], accs[ROWS];
#pragma unroll
    for (int r = 0; r < ROWS; r++) { accn[r] = 0.f; accs[r] = 0.f; }
    for (int d4 = 0; d4 < 16; d4++) {
        float wn[4], ws[4];
#pragma unroll
        for (int i = 0; i < 4; i++) {
            wn[i] = Wn1[(size_t)(d4 * 4 + i) * HIDN + t];
            ws[i] = Ws1[(size_t)(d4 * 4 + i) * HIDN + t];
        }
#pragma unroll
        for (int r = 0; r < ROWS; r++) {
            float4 xv = *(const float4*)&xn[r][d4 * 4];
            float4 sv = *(const float4*)&xs[r][d4 * 4];
            accn[r] += xv.x * wn[0] + xv.y * wn[1] + xv.z * wn[2] + xv.w * wn[3];
            accs[r] += sv.x * ws[0] + sv.y * ws[1] + sv.z * ws[2] + sv.w * ws[3];
        }
    }
    {
        float b1n = bn1[t];
        float b1s = bs1[t];
#pragma unroll
        for (int r = 0; r < ROWS; r++) {
            hn[r][t] = fmaxf(accn[r] + b1n, 0.f);
            hs[r][t] = fmaxf(accs[r] + b1s, 0.f);
        }
    }
    __syncthreads();

    const int j = t & 63;
    const int rg = (t >> 6) * 4;
    float acc[4] = {0.f, 0.f, 0.f, 0.f};
    for (int k4 = 0; k4 < HIDN / 4; k4++) {
        float wn2[4], ws2[4];
#pragma unroll
        for (int i = 0; i < 4; i++) {
            wn2[i] = Wn2[(size_t)(k4 * 4 + i) * 64 + j];
            ws2[i] = Ws2[(size_t)(k4 * 4 + i) * 64 + j];
        }
#pragma unroll
        for (int r = 0; r < 4; r++) {
            float4 hv = *(const float4*)&hn[rg + r][k4 * 4];
            float4 sv = *(const float4*)&hs[rg + r][k4 * 4];
            acc[r] += hv.x * wn2[0] + hv.y * wn2[1] + hv.z * wn2[2] + hv.w * wn2[3]
                    + sv.x * ws2[0] + sv.y * ws2[1] + sv.z * ws2[2] + sv.w * ws2[3];
        }
    }
    {
        float b2 = bn2[j] + bs2[j];
#pragma unroll
        for (int r = 0; r < 4; r++) {
            int grow = row0 + rg + r;
            if (grow < T) {
                out[(size_t)grow * 64 + j] = fmaxf(acc[r] + b2, 0.f);
            }
        }
    }
}

extern "C" void kernel_launch(void* const* d_in, const int* in_sizes, int n_in,
                              void* d_out, int out_size, void* d_ws, size_t ws_size,
                              hipStream_t stream)
{
    const float* h    = (const float*)d_in[0];
    const float* cf   = (const float*)d_in[1];
    const float* attn = (const float*)d_in[2];
    const float* Wn1  = (const float*)d_in[3];
    const float* bn1  = (const float*)d_in[4];
    const float* Wn2  = (const float*)d_in[5];
    const float* bn2  = (const float*)d_in[6];
    const float* Ws1  = (const float*)d_in[7];
    const float* bs1  = (const float*)d_in[8];
    const float* Ws2  = (const float*)d_in[9];
    const float* bs2  = (const float*)d_in[10];
    const int* src     = (const int*)d_in[11];
    const int* dst     = (const int*)d_in[12];
    const int* targets = (const int*)d_in[13];
    const int N = in_sizes[0] / 64;
    const int E = in_sizes[11];
    const int T = in_sizes[13];

    // workspace layout
    char* ws = (char*)d_ws;
    float* hnc   = (float*)ws;                       // T*64 floats (written per-row, no init)
    int* flag    = (int*)(ws + (size_t)T * 64 * 4);  // N   (zeroed)
    int* cnt     = flag + N;                         // T   (zeroed)
    int* cursor  = cnt + T;                          // T   (zeroed)
    int* count   = cursor + T;                       // 1   (zeroed)
    int* bsum    = count + 1;                        // 1024
    int* offs    = bsum + 1024;                      // T+1
    int* slot    = offs + (T + 1);                   // N
    int* esrc    = slot + N;                         // E

    // zero flag|cnt|cursor|count in one memset (~2.8 MB)
    hipMemsetAsync(flag, 0, (size_t)(N + 2 * T + 1) * sizeof(int), stream);

    k_flag_list<<<(T + 255) / 256, 256, 0, stream>>>(targets, flag, slot, count, T);
    k_hist<<<(E + 255) / 256, 256, 0, stream>>>(dst, flag, slot, cnt, E);

    const int nb = (T + SBS - 1) / SBS;              // 196 <= 1024
    k_scan1<<<nb, SBS, 0, stream>>>(cnt, offs, bsum, T);
    k_scan2<<<1, 1024, 0, stream>>>(bsum, nb);
    k_scan3<<<nb, SBS, 0, stream>>>(offs, bsum, T);

    k_scatter<<<(E + 255) / 256, 256, 0, stream>>>(src, dst, flag, slot, offs, cursor, esrc, E);

    {
        long long thr = (long long)T * 16;           // 16 lanes per unique node (U <= T)
        k_gather<<<(unsigned)((thr + 255) / 256), 256, 0, stream>>>(
            h, attn, offs, cnt, esrc, count, hnc, T);
    }

    k_mlp<<<(T + ROWS - 1) / ROWS, 256, 0, stream>>>(
        hnc, slot, cf, Wn1, bn1, Wn2, bn2, Ws1, bs1, Ws2, bs2,
        targets, (float*)d_out, T);
}

// Round 4
// 441.656 us; speedup vs baseline: 3.1883x; 1.5718x over previous
//
#include <hip/hip_runtime.h>
#include <stdint.h>

#define SBS 512

typedef short bf16x8 __attribute__((ext_vector_type(8)));
typedef short bf16x4 __attribute__((ext_vector_type(4)));
typedef float f32x4  __attribute__((ext_vector_type(4)));

__device__ __forceinline__ unsigned short f2bf(float f) {
    unsigned u = __float_as_uint(f);
    unsigned r = u + 0x7fffu + ((u >> 16) & 1u);
    return (unsigned short)(r >> 16);
}

// ---------------- unique-target list + slot map ----------------
__global__ __launch_bounds__(256) void k_flag_list(
    const int* __restrict__ targets, int* __restrict__ flag,
    int* __restrict__ slot, int* __restrict__ count, int T)
{
    int t = blockIdx.x * blockDim.x + threadIdx.x;
    if (t >= T) return;
    int g = targets[t];
    int old = atomicExch(&flag[g], 1);
    if (old == 0) {
        int u = atomicAdd(count, 1);
        slot[g] = u;
    }
}

// ---------------- per-slot in-degree histogram ----------------
__global__ __launch_bounds__(256) void k_hist(
    const int* __restrict__ dst, const int* __restrict__ flag,
    const int* __restrict__ slot, int* __restrict__ cnt, int E)
{
    int e = blockIdx.x * blockDim.x + threadIdx.x;
    if (e >= E) return;
    int d = dst[e];
    if (!flag[d]) return;
    atomicAdd(&cnt[slot[d]], 1);
}

// ---------------- exclusive scan (3-kernel, fixed length T) ----------------
__global__ __launch_bounds__(SBS) void k_scan1(
    const int* __restrict__ cnt, int* __restrict__ offs, int* __restrict__ bsum, int n)
{
    __shared__ int s[SBS];
    int t = threadIdx.x, i = blockIdx.x * SBS + t;
    int v = (i < n) ? cnt[i] : 0;
    s[t] = v; __syncthreads();
    for (int off = 1; off < SBS; off <<= 1) {
        int x = (t >= off) ? s[t - off] : 0; __syncthreads();
        s[t] += x; __syncthreads();
    }
    if (i < n) offs[i] = s[t] - v;
    if (t == SBS - 1) bsum[blockIdx.x] = s[t];
}
__global__ __launch_bounds__(1024) void k_scan2(int* __restrict__ bsum, int nb)
{
    __shared__ int s[1024];
    int t = threadIdx.x;
    int v = (t < nb) ? bsum[t] : 0;
    s[t] = v; __syncthreads();
    for (int off = 1; off < 1024; off <<= 1) {
        int x = (t >= off) ? s[t - off] : 0; __syncthreads();
        s[t] += x; __syncthreads();
    }
    if (t < nb) bsum[t] = s[t] - v;
}
__global__ __launch_bounds__(SBS) void k_scan3(
    int* __restrict__ offs, const int* __restrict__ bsum, int n)
{
    int i = blockIdx.x * SBS + threadIdx.x;
    if (i < n) offs[i] += bsum[blockIdx.x];
}

// ---------------- CSR edge scatter (stores src ids) ----------------
__global__ __launch_bounds__(256) void k_scatter(
    const int* __restrict__ src, const int* __restrict__ dst,
    const int* __restrict__ flag, const int* __restrict__ slot,
    const int* __restrict__ offs, int* __restrict__ cursor,
    int* __restrict__ esrc, int E)
{
    int e = blockIdx.x * blockDim.x + threadIdx.x;
    if (e >= E) return;
    int d = dst[e];
    if (!flag[d]) return;
    int sl = slot[d];
    int pos = atomicAdd(&cursor[sl], 1);
    esrc[offs[sl] + pos] = src[e];
}

// ---------------- gather: per-node online softmax + weighted sum ----------------
__global__ __launch_bounds__(256) void k_gather(
    const float* __restrict__ h, const float* __restrict__ attn,
    const int* __restrict__ offs, const int* __restrict__ cnt,
    const int* __restrict__ esrc, const int* __restrict__ count,
    float* __restrict__ hnc, int T)
{
    int tid = blockIdx.x * blockDim.x + threadIdx.x;
    int gid = tid >> 4;
    int lane = tid & 15;
    const int U = count[0];
    if (gid >= U) return;
    int start = offs[gid];
    int n = cnt[gid];
    float4 av = *(const float4*)(attn + lane * 4);
    float m = 0.f, den = 0.f;
    float4 o = make_float4(0.f, 0.f, 0.f, 0.f);
    for (int j = 0; j < n; j++) {
        int s = esrc[start + j];
        float4 hv = *(const float4*)(h + (size_t)s * 64 + lane * 4);
        float p = hv.x * av.x + hv.y * av.y + hv.z * av.z + hv.w * av.w;
        p += __shfl_xor(p, 1);
        p += __shfl_xor(p, 2);
        p += __shfl_xor(p, 4);
        p += __shfl_xor(p, 8);
        float e = fmaxf(p, 0.f);
        float mn = fmaxf(m, e);
        float corr = __expf(m - mn);
        float w = __expf(e - mn);
        den = den * corr + w;
        o.x = o.x * corr + w * hv.x;
        o.y = o.y * corr + w * hv.y;
        o.z = o.z * corr + w * hv.z;
        o.w = o.w * corr + w * hv.w;
        m = mn;
    }
    float4 r = make_float4(0.f, 0.f, 0.f, 0.f);
    if (n > 0) {
        float inv = 1.f / den;
        r = make_float4(o.x * inv, o.y * inv, o.z * inv, o.w * inv);
    }
    *(float4*)(hnc + (size_t)gid * 64 + lane * 4) = r;
}

// ---------------- weight prep: fp32 -> bf16, pre-swizzled fragments ----------------
// W1sw frag idx = ((s*16 + ntile)*2 + kt)*64 + lane ; elem j: W1[kt*32 + (lane>>4)*8 + j][ntile*16 + (lane&15)]
// W2sw frag idx = ((s*4 + ntile)*8 + kt)*64 + lane  ; elem j: W2[kt*32 + (lane>>4)*8 + j][ntile*16 + (lane&15)]
__global__ __launch_bounds__(256) void k_prep(
    const float* __restrict__ Wn1, const float* __restrict__ Ws1,
    const float* __restrict__ Wn2, const float* __restrict__ Ws2,
    short* __restrict__ W1sw, short* __restrict__ W2sw)
{
    int t = blockIdx.x * blockDim.x + threadIdx.x;
    if (t < 4096) {
        int lane = t & 63;
        int kt = (t >> 6) & 1;
        int nt = (t >> 7) & 15;
        int s  = (t >> 11) & 1;
        const float* W = s ? Ws1 : Wn1;  // [64][256]
        int col = nt * 16 + (lane & 15);
        int krow = kt * 32 + (lane >> 4) * 8;
        bf16x8 v;
#pragma unroll
        for (int j = 0; j < 8; j++)
            v[j] = (short)f2bf(W[(size_t)(krow + j) * 256 + col]);
        ((bf16x8*)W1sw)[t] = v;
    } else if (t < 8192) {
        int u = t - 4096;
        int lane = u & 63;
        int kt = (u >> 6) & 7;
        int nt = (u >> 9) & 3;
        int s  = (u >> 11) & 1;
        const float* W = s ? Ws2 : Wn2;  // [256][64]
        int col = nt * 16 + (lane & 15);
        int krow = kt * 32 + (lane >> 4) * 8;
        bf16x8 v;
#pragma unroll
        for (int j = 0; j < 8; j++)
            v[j] = (short)f2bf(W[(size_t)(krow + j) * 64 + col]);
        ((bf16x8*)W2sw)[u] = v;
    }
}

// ---------------- MFMA dual-MLP + relu + target gather ----------------
// 256 threads = 4 waves; wave owns 16 target rows. Per phase s (n-MLP, s-MLP):
// layer1 swapped (A=W1^T, B=X^T) -> H^T C-layout -> ds_write_b64 into XOR-swizzled
// per-wave H[16][256] bf16; layer2 normal (A=H from LDS, B=W2sw), acc persists.
__global__ __launch_bounds__(256) void k_mlp_mfma(
    const float* __restrict__ hnc, const int* __restrict__ slot,
    const float* __restrict__ cf,
    const short* __restrict__ W1sw, const short* __restrict__ W2sw,
    const float* __restrict__ bn1, const float* __restrict__ bs1,
    const float* __restrict__ bn2, const float* __restrict__ bs2,
    const int* __restrict__ targets, float* __restrict__ out, int T)
{
    __shared__ short Hlds[4][4096];   // per-wave 16 rows x 256 bf16, XOR-swizzled 16B groups
    const int tid = threadIdx.x;
    const int wave = tid >> 6, lane = tid & 63;
    const int m = lane & 15, quad = lane >> 4;
    const int mu = m & 7;
    const int rowbase = blockIdx.x * 64 + wave * 16;

    // ---- load X fragments (B-operand, X^T): lane reads X[row=m][kt*32+quad*8 ..+7]
    int grow = rowbase + m;
    int gi = (grow < T) ? grow : (T - 1);
    int g = targets[gi];
    bf16x8 bx[2][2];
    {
        const float* xr[2];
        xr[0] = hnc + (size_t)slot[g] * 64;
        xr[1] = cf + (size_t)g * 64;
#pragma unroll
        for (int s = 0; s < 2; s++) {
#pragma unroll
            for (int kt = 0; kt < 2; kt++) {
                const float* p = xr[s] + kt * 32 + quad * 8;
                f32x4 v0 = *(const f32x4*)p;
                f32x4 v1 = *(const f32x4*)(p + 4);
                bf16x8 t;
                t[0] = (short)f2bf(v0[0]); t[1] = (short)f2bf(v0[1]);
                t[2] = (short)f2bf(v0[2]); t[3] = (short)f2bf(v0[3]);
                t[4] = (short)f2bf(v1[0]); t[5] = (short)f2bf(v1[1]);
                t[6] = (short)f2bf(v1[2]); t[7] = (short)f2bf(v1[3]);
                bx[s][kt] = t;
            }
        }
    }

    short* hb = &Hlds[wave][0];
    const bf16x8* W1f = (const bf16x8*)W1sw;
    const bf16x8* W2f = (const bf16x8*)W2sw;
    f32x4 acc2[4];
#pragma unroll
    for (int i = 0; i < 4; i++) acc2[i] = (f32x4){0.f, 0.f, 0.f, 0.f};

#pragma unroll
    for (int s = 0; s < 2; s++) {
        if (s) __syncthreads();               // WAR: previous phase reads done
        const float* b1 = s ? bs1 : bn1;
        // ---- layer 1: 16 n-tiles of 16 hidden units
        for (int nt = 0; nt < 16; nt++) {
            f32x4 a = {0.f, 0.f, 0.f, 0.f};
            bf16x8 af0 = W1f[s * 2048 + nt * 128 + lane];
            bf16x8 af1 = W1f[s * 2048 + nt * 128 + 64 + lane];
            a = __builtin_amdgcn_mfma_f32_16x16x32_bf16(af0, bx[s][0], a, 0, 0, 0);
            a = __builtin_amdgcn_mfma_f32_16x16x32_bf16(af1, bx[s][1], a, 0, 0, 0);
            // D[hidden=quad*4+reg][xrow=m]; bias + relu + pack 4 consecutive hidden
            f32x4 bias = *(const f32x4*)(b1 + nt * 16 + quad * 4);
            bf16x4 pk;
            pk[0] = (short)f2bf(fmaxf(a[0] + bias[0], 0.f));
            pk[1] = (short)f2bf(fmaxf(a[1] + bias[1], 0.f));
            pk[2] = (short)f2bf(fmaxf(a[2] + bias[2], 0.f));
            pk[3] = (short)f2bf(fmaxf(a[3] + bias[3], 0.f));
            int G = 2 * nt + (quad >> 1);      // 16B-group index (8 bf16)
            *(bf16x4*)(hb + m * 256 + ((G ^ mu) << 3) + ((quad & 1) << 2)) = pk;
        }
        __syncthreads();                      // RAW: H complete
        // ---- layer 2 partial: A = H (lane reads its row m), B = W2sw
        for (int nt2 = 0; nt2 < 4; nt2++) {
#pragma unroll
            for (int kt = 0; kt < 8; kt++) {
                bf16x8 af = *(const bf16x8*)(hb + m * 256 + (((4 * kt + quad) ^ mu) << 3));
                bf16x8 bw = W2f[(size_t)((s * 4 + nt2) * 8 + kt) * 64 + lane];
                acc2[nt2] = __builtin_amdgcn_mfma_f32_16x16x32_bf16(af, bw, acc2[nt2], 0, 0, 0);
            }
        }
    }

    // ---- epilogue: D[xrow=quad*4+reg][col=m], col j = nt2*16+m
#pragma unroll
    for (int nt2 = 0; nt2 < 4; nt2++) {
        int j = nt2 * 16 + m;
        float b2 = bn2[j] + bs2[j];
#pragma unroll
        for (int r = 0; r < 4; r++) {
            int row = rowbase + quad * 4 + r;
            if (row < T) out[(size_t)row * 64 + j] = fmaxf(acc2[nt2][r] + b2, 0.f);
        }
    }
}

extern "C" void kernel_launch(void* const* d_in, const int* in_sizes, int n_in,
                              void* d_out, int out_size, void* d_ws, size_t ws_size,
                              hipStream_t stream)
{
    const float* h    = (const float*)d_in[0];
    const float* cf   = (const float*)d_in[1];
    const float* attn = (const float*)d_in[2];
    const float* Wn1  = (const float*)d_in[3];
    const float* bn1  = (const float*)d_in[4];
    const float* Wn2  = (const float*)d_in[5];
    const float* bn2  = (const float*)d_in[6];
    const float* Ws1  = (const float*)d_in[7];
    const float* bs1  = (const float*)d_in[8];
    const float* Ws2  = (const float*)d_in[9];
    const float* bs2  = (const float*)d_in[10];
    const int* src     = (const int*)d_in[11];
    const int* dst     = (const int*)d_in[12];
    const int* targets = (const int*)d_in[13];
    const int N = in_sizes[0] / 64;
    const int E = in_sizes[11];
    const int T = in_sizes[13];

    // workspace layout (64B-aligned slices)
    char* ws = (char*)d_ws;
    size_t off = 0;
    auto alloc = [&](size_t bytes) { size_t p = off; off = (off + bytes + 63) & ~(size_t)63; return p; };
    size_t o_hnc    = alloc((size_t)T * 64 * 4);
    size_t o_flag   = alloc((size_t)N * 4);
    size_t o_cnt    = alloc((size_t)T * 4);
    size_t o_cursor = alloc((size_t)T * 4);
    size_t o_count  = alloc(4);
    size_t o_bsum   = alloc(1024 * 4);
    size_t o_offs   = alloc((size_t)(T + 1) * 4);
    size_t o_slot   = alloc((size_t)N * 4);
    size_t o_esrc   = alloc((size_t)E * 4);
    size_t o_w1     = alloc(32768 * 2);
    size_t o_w2     = alloc(32768 * 2);
    (void)o_w2;

    float* hnc   = (float*)(ws + o_hnc);
    int* flag    = (int*)(ws + o_flag);
    int* cnt     = (int*)(ws + o_cnt);
    int* cursor  = (int*)(ws + o_cursor);
    int* count   = (int*)(ws + o_count);
    int* bsum    = (int*)(ws + o_bsum);
    int* offs    = (int*)(ws + o_offs);
    int* slot    = (int*)(ws + o_slot);
    int* esrc    = (int*)(ws + o_esrc);
    short* W1sw  = (short*)(ws + o_w1);
    short* W2sw  = (short*)(ws + o_w2);

    // zero flag..count (contiguous span)
    hipMemsetAsync(flag, 0, (o_count + 4) - o_flag, stream);

    k_prep<<<32, 256, 0, stream>>>(Wn1, Ws1, Wn2, Ws2, W1sw, W2sw);
    k_flag_list<<<(T + 255) / 256, 256, 0, stream>>>(targets, flag, slot, count, T);
    k_hist<<<(E + 255) / 256, 256, 0, stream>>>(dst, flag, slot, cnt, E);

    const int nb = (T + SBS - 1) / SBS;
    k_scan1<<<nb, SBS, 0, stream>>>(cnt, offs, bsum, T);
    k_scan2<<<1, 1024, 0, stream>>>(bsum, nb);
    k_scan3<<<nb, SBS, 0, stream>>>(offs, bsum, T);

    k_scatter<<<(E + 255) / 256, 256, 0, stream>>>(src, dst, flag, slot, offs, cursor, esrc, E);

    {
        long long thr = (long long)T * 16;
        k_gather<<<(unsigned)((thr + 255) / 256), 256, 0, stream>>>(
            h, attn, offs, cnt, esrc, count, hnc, T);
    }

    k_mlp_mfma<<<(T + 63) / 64, 256, 0, stream>>>(
        hnc, slot, cf, W1sw, W2sw, bn1, bs1, bn2, bs2,
        targets, (float*)d_out, T);
}